// Round 3
// baseline (210.031 us; speedup 1.0000x reference)
//
#include <hip/hip_runtime.h>

// B=4, S=4096, d_model=256, d_k=d_v=64
#define B_    4
#define S_    4096
#define DM    256
#define DK    64
#define NROWS (B_ * S_)        // 16384
#define LOG2E 1.4426950408889634f

typedef __attribute__((ext_vector_type(8))) short bfrag;   // 8 bf16 (4 VGPRs)
typedef __attribute__((ext_vector_type(4))) float ffrag;   // 4 f32 acc

// f32 -> bf16 round-to-nearest-even (inputs finite)
__device__ __forceinline__ unsigned bf16_rne_hi(float x) {
    unsigned u = __float_as_uint(x);
    return u + 0x7fffu + ((u >> 16) & 1u);
}
__device__ __forceinline__ unsigned short f2bf(float x) {
    return (unsigned short)(bf16_rne_hi(x) >> 16);
}
__device__ __forceinline__ unsigned pack_bf16x2(float lo, float hi) {
    return (bf16_rne_hi(hi) & 0xffff0000u) | (bf16_rne_hi(lo) >> 16);
}

// ---------------------------------------------------------------------------
// Fused prep + projection, one launch (512 blocks):
//   blocks 0..255  : vT_perm[b][d][pos] = bf16(v[b][key][d]), pos=2c -> key c,
//                    pos=2c+1 -> key c+16 (matches P pair-packing in attn)
//   blocks 256..511: qp/kp = bf16(relu(x . w^T) * scale) via MFMA; w is
//                    converted f32->bf16 into LDS per block (stride 264 ush
//                    -> 2-way banks = free). q-scale folds 1/8 * log2(e) so
//                    attn uses exp2 directly.
// ---------------------------------------------------------------------------
__global__ __launch_bounds__(256) void fused_prep(
    const float* __restrict__ q, const float* __restrict__ k,
    const float* __restrict__ v, const float* __restrict__ wq,
    const float* __restrict__ wk, unsigned short* __restrict__ vT,
    unsigned short* __restrict__ qpb, unsigned short* __restrict__ kpb)
{
    __shared__ __align__(16) char smem[64 * 264 * 2];   // 33792 B (union)
    const int blk  = blockIdx.x;
    const int lane = threadIdx.x & 63, w = threadIdx.x >> 6;

    if (blk < 256) {
        // ---- vT transpose+permute ----
        float (*tile)[65] = (float(*)[65])smem;
        const int b = blk >> 6, s0 = (blk & 63) * 64;
#pragma unroll
        for (int i = 0; i < 16; ++i) {
            const int sl = i * 4 + w;
            tile[sl][lane] = v[(b * S_ + s0 + sl) * DK + lane];
        }
        __syncthreads();
#pragma unroll
        for (int i = 0; i < 16; ++i) {
            const int d = i * 4 + w;
            const int t32 = lane >> 5, pos = lane & 31;
            const int keyl = t32 * 32 + ((pos & 1) ? (pos >> 1) + 16 : (pos >> 1));
            vT[(b * DK + d) * S_ + s0 + lane] = f2bf(tile[keyl][d]);
        }
    } else {
        // ---- projection ----
        unsigned short* wlds = (unsigned short*)smem;   // [64][264] bf16
        const int pb = blk - 256;
        const int half = pb >> 7, rblk = pb & 127;
        const float* x;
        const float* wsrc;
        unsigned short* o;
        float scale;
        if (half == 0) { x = q; wsrc = wq; o = qpb; scale = 0.125f * LOG2E; }
        else           { x = k; wsrc = wk; o = kpb; scale = 1.0f; }

        // stage w (64x256 f32 -> bf16 LDS, stride 264)
#pragma unroll
        for (int i = 0; i < 16; ++i) {
            const int idx4 = i * 256 + threadIdx.x;     // float4 index, < 4096
            const int r = idx4 >> 6, c4 = idx4 & 63;
            const float4 wv = ((const float4*)wsrc)[idx4];
            uint2 pk;
            pk.x = pack_bf16x2(wv.x, wv.y);
            pk.y = pack_bf16x2(wv.z, wv.w);
            *(uint2*)&wlds[r * 264 + c4 * 4] = pk;
        }
        __syncthreads();

        const int m = lane & 15, quad = lane >> 4;
        const int rows0 = rblk * 128 + w * 32;

        ffrag acc[2][4];
#pragma unroll
        for (int mt = 0; mt < 2; ++mt)
#pragma unroll
            for (int dt = 0; dt < 4; ++dt) acc[mt][dt] = (ffrag)(0.0f);

#pragma unroll
        for (int kf = 0; kf < 8; ++kf) {
            bfrag A[2];
#pragma unroll
            for (int mt = 0; mt < 2; ++mt) {
                const float4* xr = (const float4*)&x[(rows0 + mt * 16 + m) * DM + kf * 32 + quad * 8];
                const float4 a0 = xr[0], a1 = xr[1];
                union { bfrag v; unsigned u[4]; } pk;
                pk.u[0] = pack_bf16x2(a0.x, a0.y);
                pk.u[1] = pack_bf16x2(a0.z, a0.w);
                pk.u[2] = pack_bf16x2(a1.x, a1.y);
                pk.u[3] = pack_bf16x2(a1.z, a1.w);
                A[mt] = pk.v;
            }
#pragma unroll
            for (int dt = 0; dt < 4; ++dt) {
                const bfrag Bf = *(const bfrag*)&wlds[(dt * 16 + m) * 264 + kf * 32 + quad * 8];
                acc[0][dt] = __builtin_amdgcn_mfma_f32_16x16x32_bf16(A[0], Bf, acc[0][dt], 0, 0, 0);
                acc[1][dt] = __builtin_amdgcn_mfma_f32_16x16x32_bf16(A[1], Bf, acc[1][dt], 0, 0, 0);
            }
        }
#pragma unroll
        for (int mt = 0; mt < 2; ++mt)
#pragma unroll
            for (int dt = 0; dt < 4; ++dt)
#pragma unroll
                for (int r = 0; r < 4; ++r)
                    o[(rows0 + mt * 16 + quad * 4 + r) * DK + dt * 16 + m] =
                        f2bf(fmaxf(acc[mt][dt][r], 0.0f) * scale);
    }
}

// ---------------------------------------------------------------------------
// Attention, software-pipelined: per iteration, prefetch tile jj+1's K/V
// frags (global latency hidden one full iteration), compute QK + exp for jj,
// and run PV for jj-1 (so the P LDS write->read round-trip is also hidden).
// Single P buffer is safe: per-wave DS ops execute in order. One-pass
// num/den (scores bounded, no max-rescale); col-0 mask -> e = 0.
// ---------------------------------------------------------------------------
__global__ __launch_bounds__(256, 3) void attn_mfma(
    const unsigned short* __restrict__ qp, const unsigned short* __restrict__ kp,
    const unsigned short* __restrict__ vT, float* __restrict__ num_part,
    float* __restrict__ den_part)
{
    __shared__ __align__(16) char smem[20480];   // P buffers (10240) U epilogue red
    unsigned short* Plds = (unsigned short*)smem;   // [4][32*40]
    float* red0 = (float*)smem;                      // epilogue: [2][2560]
    float* red1 = (float*)smem + 2560;

    const int lane = threadIdx.x & 63, w = threadIdx.x >> 6;
    const int m = lane & 15, quad = lane >> 4;
    const int qg = blockIdx.x;            // 0..511
    const int qbase = qg * 32;
    const int b = qg >> 7;
    const int kstart = (blockIdx.y * 4 + w) * 512;

    bfrag qa[2][2];
#pragma unroll
    for (int mt = 0; mt < 2; ++mt)
#pragma unroll
        for (int kf = 0; kf < 2; ++kf)
            qa[mt][kf] = *(const bfrag*)&qp[(qbase + mt * 16 + m) * DK + kf * 32 + quad * 8];

    ffrag oacc[2][4];
    float dacc[2][4];
#pragma unroll
    for (int mt = 0; mt < 2; ++mt) {
#pragma unroll
        for (int dt = 0; dt < 4; ++dt) oacc[mt][dt] = (ffrag)(0.0f);
#pragma unroll
        for (int r = 0; r < 4; ++r) dacc[mt][r] = 0.0f;
    }

    const unsigned short* kpb = kp + b * S_ * DK;
    const unsigned short* vtb = vT + b * DK * S_;
    unsigned short* Pw = Plds + w * 1280;

    // preload tile 0
    bfrag kcur[2][2], vcur[4];
#pragma unroll
    for (int kt = 0; kt < 2; ++kt)
#pragma unroll
        for (int kf = 0; kf < 2; ++kf)
            kcur[kt][kf] = *(const bfrag*)&kpb[(kstart + kt * 16 + m) * DK + kf * 32 + quad * 8];
#pragma unroll
    for (int dt = 0; dt < 4; ++dt)
        vcur[dt] = *(const bfrag*)&vtb[(dt * 16 + m) * S_ + kstart + quad * 8];

    bfrag pa0, pa1, vprev[4];

#pragma unroll
    for (int jj = 0; jj < 16; ++jj) {
        const int kb = kstart + jj * 32;

        // prefetch tile jj+1
        bfrag knxt[2][2], vnxt[4];
        if (jj < 15) {
            const int kb2 = kb + 32;
#pragma unroll
            for (int kt = 0; kt < 2; ++kt)
#pragma unroll
                for (int kf = 0; kf < 2; ++kf)
                    knxt[kt][kf] = *(const bfrag*)&kpb[(kb2 + kt * 16 + m) * DK + kf * 32 + quad * 8];
#pragma unroll
            for (int dt = 0; dt < 4; ++dt)
                vnxt[dt] = *(const bfrag*)&vtb[(dt * 16 + m) * S_ + kb2 + quad * 8];
        }

        // scores (log2-domain: 1/8*log2e folded into qp)
        ffrag s[2][2];
#pragma unroll
        for (int mt = 0; mt < 2; ++mt)
#pragma unroll
            for (int kt = 0; kt < 2; ++kt) {
                ffrag t = __builtin_amdgcn_mfma_f32_16x16x32_bf16(qa[mt][0], kcur[kt][0], (ffrag)(0.0f), 0, 0, 0);
                s[mt][kt] = __builtin_amdgcn_mfma_f32_16x16x32_bf16(qa[mt][1], kcur[kt][1], t, 0, 0, 0);
            }

        const bool mask0 = (kb == 0) && (m == 0);
#pragma unroll
        for (int mt = 0; mt < 2; ++mt)
#pragma unroll
            for (int r = 0; r < 4; ++r) {
                float e0 = exp2f(s[mt][0][r]);
                float e1 = exp2f(s[mt][1][r]);
                if (mask0) e0 = 0.0f;
                dacc[mt][r] += e0 + e1;
                *(unsigned*)&Pw[(mt * 16 + quad * 4 + r) * 40 + m * 2] = pack_bf16x2(e0, e1);
            }

        // PV for tile jj-1 (overlaps this tile's LDS round-trip)
        if (jj > 0) {
#pragma unroll
            for (int dt = 0; dt < 4; ++dt) {
                oacc[0][dt] = __builtin_amdgcn_mfma_f32_16x16x32_bf16(pa0, vprev[dt], oacc[0][dt], 0, 0, 0);
                oacc[1][dt] = __builtin_amdgcn_mfma_f32_16x16x32_bf16(pa1, vprev[dt], oacc[1][dt], 0, 0, 0);
            }
        }

        // read P(jj) as A-frags (per-wave DS in-order: sees this tile's write)
        pa0 = *(const bfrag*)&Pw[(m) * 40 + quad * 8];
        pa1 = *(const bfrag*)&Pw[(16 + m) * 40 + quad * 8];
#pragma unroll
        for (int dt = 0; dt < 4; ++dt) vprev[dt] = vcur[dt];
        if (jj < 15) {
#pragma unroll
            for (int kt = 0; kt < 2; ++kt)
#pragma unroll
                for (int kf = 0; kf < 2; ++kf) kcur[kt][kf] = knxt[kt][kf];
#pragma unroll
            for (int dt = 0; dt < 4; ++dt) vcur[dt] = vnxt[dt];
        }
    }
    // final PV (tile 15)
#pragma unroll
    for (int dt = 0; dt < 4; ++dt) {
        oacc[0][dt] = __builtin_amdgcn_mfma_f32_16x16x32_bf16(pa0, vprev[dt], oacc[0][dt], 0, 0, 0);
        oacc[1][dt] = __builtin_amdgcn_mfma_f32_16x16x32_bf16(pa1, vprev[dt], oacc[1][dt], 0, 0, 0);
    }

    // den: reduce over the 16 key-lanes within each quad group
#pragma unroll
    for (int mt = 0; mt < 2; ++mt)
#pragma unroll
        for (int r = 0; r < 4; ++r) {
            float d = dacc[mt][r];
            d += __shfl_xor(d, 1, 64);
            d += __shfl_xor(d, 2, 64);
            d += __shfl_xor(d, 4, 64);
            d += __shfl_xor(d, 8, 64);
            dacc[mt][r] = d;
        }

    // cross-wave tree reduce (reuses P LDS; P is dead)
    __syncthreads();
    float* red[2] = { red0, red1 };
    if (w >= 2) {
#pragma unroll
        for (int mt = 0; mt < 2; ++mt) {
#pragma unroll
            for (int dt = 0; dt < 4; ++dt)
#pragma unroll
                for (int r = 0; r < 4; ++r)
                    red[w - 2][((mt * 4 + dt) * 4 + r) * 64 + lane] = oacc[mt][dt][r];
#pragma unroll
            for (int r = 0; r < 4; ++r)
                red[w - 2][2048 + (mt * 4 + r) * 64 + lane] = dacc[mt][r];
        }
    }
    __syncthreads();
    if (w < 2) {
#pragma unroll
        for (int mt = 0; mt < 2; ++mt) {
#pragma unroll
            for (int dt = 0; dt < 4; ++dt)
#pragma unroll
                for (int r = 0; r < 4; ++r)
                    oacc[mt][dt][r] += red[w][((mt * 4 + dt) * 4 + r) * 64 + lane];
#pragma unroll
            for (int r = 0; r < 4; ++r)
                dacc[mt][r] += red[w][2048 + (mt * 4 + r) * 64 + lane];
        }
    }
    __syncthreads();
    if (w == 1) {
#pragma unroll
        for (int mt = 0; mt < 2; ++mt) {
#pragma unroll
            for (int dt = 0; dt < 4; ++dt)
#pragma unroll
                for (int r = 0; r < 4; ++r)
                    red0[((mt * 4 + dt) * 4 + r) * 64 + lane] = oacc[mt][dt][r];
#pragma unroll
            for (int r = 0; r < 4; ++r)
                red0[2048 + (mt * 4 + r) * 64 + lane] = dacc[mt][r];
        }
    }
    __syncthreads();
    if (w == 0) {
        const int gy = blockIdx.y;
#pragma unroll
        for (int mt = 0; mt < 2; ++mt) {
#pragma unroll
            for (int dt = 0; dt < 4; ++dt)
#pragma unroll
                for (int r = 0; r < 4; ++r) {
                    const float nv = oacc[mt][dt][r] + red0[((mt * 4 + dt) * 4 + r) * 64 + lane];
                    num_part[(size_t)gy * NROWS * DK +
                             (qbase + mt * 16 + quad * 4 + r) * DK + dt * 16 + m] = nv;
                }
#pragma unroll
            for (int r = 0; r < 4; ++r) {
                const float dv = dacc[mt][r] + red0[2048 + (mt * 4 + r) * 64 + lane];
                if (m == 0)
                    den_part[gy * NROWS + qbase + mt * 16 + quad * 4 + r] = dv;
            }
        }
    }
}

// ---------------------------------------------------------------------------
__global__ __launch_bounds__(256) void finalize_kernel(
    const float* __restrict__ num_part, const float* __restrict__ den_part,
    float* __restrict__ out)
{
    const int i4 = blockIdx.x * 256 + threadIdx.x;   // float4 index, < 262144
    const int row = i4 >> 4;
    const float4 a = ((const float4*)num_part)[i4];
    const float4 c = ((const float4*)(num_part + (size_t)NROWS * DK))[i4];
    const float inv = 1.0f / (den_part[row] + den_part[NROWS + row]);
    float4 o;
    o.x = (a.x + c.x) * inv;
    o.y = (a.y + c.y) * inv;
    o.z = (a.z + c.z) * inv;
    o.w = (a.w + c.w) * inv;
    ((float4*)out)[i4] = o;
}

// ---------------------------------------------------------------------------
extern "C" void kernel_launch(void* const* d_in, const int* in_sizes, int n_in,
                              void* d_out, int out_size, void* d_ws, size_t ws_size,
                              hipStream_t stream)
{
    const float* q  = (const float*)d_in[0];
    const float* k  = (const float*)d_in[1];
    const float* v  = (const float*)d_in[2];
    const float* wq = (const float*)d_in[3];
    const float* wk = (const float*)d_in[4];
    float* out = (float*)d_out;

    // ws: qpb 2M | kpb 2M | vT 2M | num_part 8M | den_part 128K
    char* p = (char*)d_ws;
    unsigned short* qpb = (unsigned short*)p;   p += (size_t)NROWS * DK * 2;
    unsigned short* kpb = (unsigned short*)p;   p += (size_t)NROWS * DK * 2;
    unsigned short* vT  = (unsigned short*)p;   p += (size_t)B_ * DK * S_ * 2;
    float* num_part     = (float*)p;            p += (size_t)2 * NROWS * DK * 4;
    float* den_part     = (float*)p;

    fused_prep<<<512, 256, 0, stream>>>(q, k, v, wq, wk, vT, qpb, kpb);
    attn_mfma<<<dim3(512, 2), 256, 0, stream>>>(qpb, kpb, vT, num_part, den_part);
    finalize_kernel<<<NROWS * DK / 4 / 256, 256, 0, stream>>>(num_part, den_part, out);
}

// Round 4
// 153.705 us; speedup vs baseline: 1.3665x; 1.3665x over previous
//
#include <hip/hip_runtime.h>

// B=4, S=4096, d_model=256, d_k=d_v=64
#define B_    4
#define S_    4096
#define DM    256
#define DK    64
#define NROWS (B_ * S_)        // 16384
#define LOG2E 1.4426950408889634f

typedef __attribute__((ext_vector_type(8))) short bfrag;   // 8 bf16 (4 VGPRs)
typedef __attribute__((ext_vector_type(4))) float ffrag;   // 4 f32 acc

// f32 -> bf16 round-to-nearest-even (inputs finite)
__device__ __forceinline__ unsigned bf16_rne_hi(float x) {
    unsigned u = __float_as_uint(x);
    return u + 0x7fffu + ((u >> 16) & 1u);
}
__device__ __forceinline__ unsigned short f2bf(float x) {
    return (unsigned short)(bf16_rne_hi(x) >> 16);
}
__device__ __forceinline__ unsigned pack_bf16x2(float lo, float hi) {
    return (bf16_rne_hi(hi) & 0xffff0000u) | (bf16_rne_hi(lo) >> 16);
}

// ---------------------------------------------------------------------------
// Fused prep + projection, one launch (512 blocks):
//   blocks 0..255  : vT_perm[b][d][pos] = bf16(v[b][key][d]), pos=2c -> key c,
//                    pos=2c+1 -> key c+16 (matches P pair-packing in attn)
//   blocks 256..511: qp/kp = bf16(relu(x . w^T) * scale) via MFMA; w staged
//                    f32->bf16 in LDS (stride 264 ush -> 2-way banks = free).
//                    q-scale folds 1/8 * log2(e) so attn uses exp2 directly.
// ---------------------------------------------------------------------------
__global__ __launch_bounds__(256) void fused_prep(
    const float* __restrict__ q, const float* __restrict__ k,
    const float* __restrict__ v, const float* __restrict__ wq,
    const float* __restrict__ wk, unsigned short* __restrict__ vT,
    unsigned short* __restrict__ qpb, unsigned short* __restrict__ kpb)
{
    __shared__ __align__(16) char smem[64 * 264 * 2];   // 33792 B (union)
    const int blk  = blockIdx.x;
    const int lane = threadIdx.x & 63, w = threadIdx.x >> 6;

    if (blk < 256) {
        // ---- vT transpose+permute ----
        float (*tile)[65] = (float(*)[65])smem;
        const int b = blk >> 6, s0 = (blk & 63) * 64;
#pragma unroll
        for (int i = 0; i < 16; ++i) {
            const int sl = i * 4 + w;
            tile[sl][lane] = v[(b * S_ + s0 + sl) * DK + lane];
        }
        __syncthreads();
#pragma unroll
        for (int i = 0; i < 16; ++i) {
            const int d = i * 4 + w;
            const int t32 = lane >> 5, pos = lane & 31;
            const int keyl = t32 * 32 + ((pos & 1) ? (pos >> 1) + 16 : (pos >> 1));
            vT[(b * DK + d) * S_ + s0 + lane] = f2bf(tile[keyl][d]);
        }
    } else {
        // ---- projection ----
        unsigned short* wlds = (unsigned short*)smem;   // [64][264] bf16
        const int pb = blk - 256;
        const int half = pb >> 7, rblk = pb & 127;
        const float* x;
        const float* wsrc;
        unsigned short* o;
        float scale;
        if (half == 0) { x = q; wsrc = wq; o = qpb; scale = 0.125f * LOG2E; }
        else           { x = k; wsrc = wk; o = kpb; scale = 1.0f; }

        // stage w (64x256 f32 -> bf16 LDS, stride 264)
#pragma unroll
        for (int i = 0; i < 16; ++i) {
            const int idx4 = i * 256 + threadIdx.x;     // float4 index, < 4096
            const int r = idx4 >> 6, c4 = idx4 & 63;
            const float4 wv = ((const float4*)wsrc)[idx4];
            uint2 pk;
            pk.x = pack_bf16x2(wv.x, wv.y);
            pk.y = pack_bf16x2(wv.z, wv.w);
            *(uint2*)&wlds[r * 264 + c4 * 4] = pk;
        }
        __syncthreads();

        const int m = lane & 15, quad = lane >> 4;
        const int rows0 = rblk * 128 + w * 32;

        ffrag acc[2][4];
#pragma unroll
        for (int mt = 0; mt < 2; ++mt)
#pragma unroll
            for (int dt = 0; dt < 4; ++dt) acc[mt][dt] = (ffrag)(0.0f);

#pragma unroll
        for (int kf = 0; kf < 8; ++kf) {
            bfrag A[2];
#pragma unroll
            for (int mt = 0; mt < 2; ++mt) {
                const float4* xr = (const float4*)&x[(rows0 + mt * 16 + m) * DM + kf * 32 + quad * 8];
                const float4 a0 = xr[0], a1 = xr[1];
                union { bfrag v; unsigned u[4]; } pk;
                pk.u[0] = pack_bf16x2(a0.x, a0.y);
                pk.u[1] = pack_bf16x2(a0.z, a0.w);
                pk.u[2] = pack_bf16x2(a1.x, a1.y);
                pk.u[3] = pack_bf16x2(a1.z, a1.w);
                A[mt] = pk.v;
            }
#pragma unroll
            for (int dt = 0; dt < 4; ++dt) {
                const bfrag Bf = *(const bfrag*)&wlds[(dt * 16 + m) * 264 + kf * 32 + quad * 8];
                acc[0][dt] = __builtin_amdgcn_mfma_f32_16x16x32_bf16(A[0], Bf, acc[0][dt], 0, 0, 0);
                acc[1][dt] = __builtin_amdgcn_mfma_f32_16x16x32_bf16(A[1], Bf, acc[1][dt], 0, 0, 0);
            }
        }
#pragma unroll
        for (int mt = 0; mt < 2; ++mt)
#pragma unroll
            for (int dt = 0; dt < 4; ++dt)
#pragma unroll
                for (int r = 0; r < 4; ++r)
                    o[(rows0 + mt * 16 + quad * 4 + r) * DK + dt * 16 + m] =
                        f2bf(fmaxf(acc[mt][dt][r], 0.0f) * scale);
    }
}

// ---------------------------------------------------------------------------
// Attention, software-pipelined (spill-safe version):
//  - ping-pong register buffers kbuf[2]/vbuf[2], #pragma unroll 2 so indices
//    are static; NO full unroll, NO launch_bounds occupancy cap.
//  - per iter jj: prefetch K(jj+1); PV(jj-1) (operands ready: pa regs +
//    vbuf[p^1], which dies here); prefetch V(jj+1) into the freed slot;
//    QK(jj) on kbuf[p] (loaded a full iter ago); exp; P->LDS; P->pa regs.
//  - single P LDS buffer per wave is safe: per-wave DS ops are in-order.
//  One-pass num/den (scores bounded, no max-rescale); col-0 mask -> e = 0.
// ---------------------------------------------------------------------------
__global__ __launch_bounds__(256) void attn_mfma(
    const unsigned short* __restrict__ qp, const unsigned short* __restrict__ kp,
    const unsigned short* __restrict__ vT, float* __restrict__ num_part,
    float* __restrict__ den_part)
{
    __shared__ __align__(16) char smem[20480];   // P buffers (10240) U epilogue red
    unsigned short* Plds = (unsigned short*)smem;   // [4][32*40]
    float* red0 = (float*)smem;                      // epilogue: [2][2560]
    float* red1 = (float*)smem + 2560;

    const int lane = threadIdx.x & 63, w = threadIdx.x >> 6;
    const int m = lane & 15, quad = lane >> 4;
    const int qg = blockIdx.x;            // 0..511
    const int qbase = qg * 32;
    const int b = qg >> 7;
    const int kstart = (blockIdx.y * 4 + w) * 512;

    bfrag qa[2][2];
#pragma unroll
    for (int mt = 0; mt < 2; ++mt)
#pragma unroll
        for (int kf = 0; kf < 2; ++kf)
            qa[mt][kf] = *(const bfrag*)&qp[(qbase + mt * 16 + m) * DK + kf * 32 + quad * 8];

    ffrag oacc[2][4];
    float dacc[2][4];
#pragma unroll
    for (int mt = 0; mt < 2; ++mt) {
#pragma unroll
        for (int dt = 0; dt < 4; ++dt) oacc[mt][dt] = (ffrag)(0.0f);
#pragma unroll
        for (int r = 0; r < 4; ++r) dacc[mt][r] = 0.0f;
    }

    const unsigned short* kpb = kp + b * S_ * DK;
    const unsigned short* vtb = vT + b * DK * S_;
    unsigned short* Pw = Plds + w * 1280;

    // preload tile 0 into slot 0
    bfrag kbuf[2][2][2], vbuf[2][4];
#pragma unroll
    for (int kt = 0; kt < 2; ++kt)
#pragma unroll
        for (int kf = 0; kf < 2; ++kf)
            kbuf[0][kt][kf] = *(const bfrag*)&kpb[(kstart + kt * 16 + m) * DK + kf * 32 + quad * 8];
#pragma unroll
    for (int dt = 0; dt < 4; ++dt)
        vbuf[0][dt] = *(const bfrag*)&vtb[(dt * 16 + m) * S_ + kstart + quad * 8];

    bfrag pa0, pa1;

#pragma unroll 2
    for (int jj = 0; jj < 16; ++jj) {
        const int p  = jj & 1;
        const int kb = kstart + jj * 32;

        // 1) prefetch K(jj+1) -> kbuf[p^1]
        if (jj < 15) {
            const int kb2 = kb + 32;
#pragma unroll
            for (int kt = 0; kt < 2; ++kt)
#pragma unroll
                for (int kf = 0; kf < 2; ++kf)
                    kbuf[p ^ 1][kt][kf] =
                        *(const bfrag*)&kpb[(kb2 + kt * 16 + m) * DK + kf * 32 + quad * 8];
        }

        // 2) PV(jj-1): pa + vbuf[p^1] (V(jj-1) dies here)
        if (jj > 0) {
#pragma unroll
            for (int dt = 0; dt < 4; ++dt) {
                oacc[0][dt] = __builtin_amdgcn_mfma_f32_16x16x32_bf16(pa0, vbuf[p ^ 1][dt], oacc[0][dt], 0, 0, 0);
                oacc[1][dt] = __builtin_amdgcn_mfma_f32_16x16x32_bf16(pa1, vbuf[p ^ 1][dt], oacc[1][dt], 0, 0, 0);
            }
        }

        // 3) prefetch V(jj+1) -> vbuf[p^1] (freed slot)
        if (jj < 15) {
#pragma unroll
            for (int dt = 0; dt < 4; ++dt)
                vbuf[p ^ 1][dt] = *(const bfrag*)&vtb[(dt * 16 + m) * S_ + kb + 32 + quad * 8];
        }

        // 4) QK(jj) on kbuf[p] (loaded one iteration ago)
        ffrag s[2][2];
#pragma unroll
        for (int mt = 0; mt < 2; ++mt)
#pragma unroll
            for (int kt = 0; kt < 2; ++kt) {
                ffrag t = __builtin_amdgcn_mfma_f32_16x16x32_bf16(qa[mt][0], kbuf[p][kt][0], (ffrag)(0.0f), 0, 0, 0);
                s[mt][kt] = __builtin_amdgcn_mfma_f32_16x16x32_bf16(qa[mt][1], kbuf[p][kt][1], t, 0, 0, 0);
            }

        // 5) exp (log2-domain), mask col 0, den, pack pairs -> LDS
        const bool mask0 = (kb == 0) && (m == 0);
#pragma unroll
        for (int mt = 0; mt < 2; ++mt)
#pragma unroll
            for (int r = 0; r < 4; ++r) {
                float e0 = exp2f(s[mt][0][r]);
                float e1 = exp2f(s[mt][1][r]);
                if (mask0) e0 = 0.0f;
                dacc[mt][r] += e0 + e1;
                *(unsigned*)&Pw[(mt * 16 + quad * 4 + r) * 40 + m * 2] = pack_bf16x2(e0, e1);
            }

        // 6) read P(jj) as A-frags into regs (per-wave DS in-order)
        pa0 = *(const bfrag*)&Pw[(m) * 40 + quad * 8];
        pa1 = *(const bfrag*)&Pw[(16 + m) * 40 + quad * 8];
    }
    // final PV (tile 15): V(15) is in vbuf[1]
#pragma unroll
    for (int dt = 0; dt < 4; ++dt) {
        oacc[0][dt] = __builtin_amdgcn_mfma_f32_16x16x32_bf16(pa0, vbuf[1][dt], oacc[0][dt], 0, 0, 0);
        oacc[1][dt] = __builtin_amdgcn_mfma_f32_16x16x32_bf16(pa1, vbuf[1][dt], oacc[1][dt], 0, 0, 0);
    }

    // den: reduce over the 16 key-lanes within each quad group
#pragma unroll
    for (int mt = 0; mt < 2; ++mt)
#pragma unroll
        for (int r = 0; r < 4; ++r) {
            float d = dacc[mt][r];
            d += __shfl_xor(d, 1, 64);
            d += __shfl_xor(d, 2, 64);
            d += __shfl_xor(d, 4, 64);
            d += __shfl_xor(d, 8, 64);
            dacc[mt][r] = d;
        }

    // cross-wave tree reduce (reuses P LDS; P is dead)
    __syncthreads();
    float* red[2] = { red0, red1 };
    if (w >= 2) {
#pragma unroll
        for (int mt = 0; mt < 2; ++mt) {
#pragma unroll
            for (int dt = 0; dt < 4; ++dt)
#pragma unroll
                for (int r = 0; r < 4; ++r)
                    red[w - 2][((mt * 4 + dt) * 4 + r) * 64 + lane] = oacc[mt][dt][r];
#pragma unroll
            for (int r = 0; r < 4; ++r)
                red[w - 2][2048 + (mt * 4 + r) * 64 + lane] = dacc[mt][r];
        }
    }
    __syncthreads();
    if (w < 2) {
#pragma unroll
        for (int mt = 0; mt < 2; ++mt) {
#pragma unroll
            for (int dt = 0; dt < 4; ++dt)
#pragma unroll
                for (int r = 0; r < 4; ++r)
                    oacc[mt][dt][r] += red[w][((mt * 4 + dt) * 4 + r) * 64 + lane];
#pragma unroll
            for (int r = 0; r < 4; ++r)
                dacc[mt][r] += red[w][2048 + (mt * 4 + r) * 64 + lane];
        }
    }
    __syncthreads();
    if (w == 1) {
#pragma unroll
        for (int mt = 0; mt < 2; ++mt) {
#pragma unroll
            for (int dt = 0; dt < 4; ++dt)
#pragma unroll
                for (int r = 0; r < 4; ++r)
                    red0[((mt * 4 + dt) * 4 + r) * 64 + lane] = oacc[mt][dt][r];
#pragma unroll
            for (int r = 0; r < 4; ++r)
                red0[2048 + (mt * 4 + r) * 64 + lane] = dacc[mt][r];
        }
    }
    __syncthreads();
    if (w == 0) {
        const int gy = blockIdx.y;
#pragma unroll
        for (int mt = 0; mt < 2; ++mt) {
#pragma unroll
            for (int dt = 0; dt < 4; ++dt)
#pragma unroll
                for (int r = 0; r < 4; ++r) {
                    const float nv = oacc[mt][dt][r] + red0[((mt * 4 + dt) * 4 + r) * 64 + lane];
                    num_part[(size_t)gy * NROWS * DK +
                             (qbase + mt * 16 + quad * 4 + r) * DK + dt * 16 + m] = nv;
                }
#pragma unroll
            for (int r = 0; r < 4; ++r) {
                const float dv = dacc[mt][r] + red0[2048 + (mt * 4 + r) * 64 + lane];
                if (m == 0)
                    den_part[gy * NROWS + qbase + mt * 16 + quad * 4 + r] = dv;
            }
        }
    }
}

// ---------------------------------------------------------------------------
__global__ __launch_bounds__(256) void finalize_kernel(
    const float* __restrict__ num_part, const float* __restrict__ den_part,
    float* __restrict__ out)
{
    const int i4 = blockIdx.x * 256 + threadIdx.x;   // float4 index, < 262144
    const int row = i4 >> 4;
    const float4 a = ((const float4*)num_part)[i4];
    const float4 c = ((const float4*)(num_part + (size_t)NROWS * DK))[i4];
    const float inv = 1.0f / (den_part[row] + den_part[NROWS + row]);
    float4 o;
    o.x = (a.x + c.x) * inv;
    o.y = (a.y + c.y) * inv;
    o.z = (a.z + c.z) * inv;
    o.w = (a.w + c.w) * inv;
    ((float4*)out)[i4] = o;
}

// ---------------------------------------------------------------------------
extern "C" void kernel_launch(void* const* d_in, const int* in_sizes, int n_in,
                              void* d_out, int out_size, void* d_ws, size_t ws_size,
                              hipStream_t stream)
{
    const float* q  = (const float*)d_in[0];
    const float* k  = (const float*)d_in[1];
    const float* v  = (const float*)d_in[2];
    const float* wq = (const float*)d_in[3];
    const float* wk = (const float*)d_in[4];
    float* out = (float*)d_out;

    // ws: qpb 2M | kpb 2M | vT 2M | num_part 8M | den_part 128K
    char* p = (char*)d_ws;
    unsigned short* qpb = (unsigned short*)p;   p += (size_t)NROWS * DK * 2;
    unsigned short* kpb = (unsigned short*)p;   p += (size_t)NROWS * DK * 2;
    unsigned short* vT  = (unsigned short*)p;   p += (size_t)B_ * DK * S_ * 2;
    float* num_part     = (float*)p;            p += (size_t)2 * NROWS * DK * 4;
    float* den_part     = (float*)p;

    fused_prep<<<512, 256, 0, stream>>>(q, k, v, wq, wk, vT, qpb, kpb);
    attn_mfma<<<dim3(512, 2), 256, 0, stream>>>(qpb, kpb, vT, num_part, den_part);
    finalize_kernel<<<NROWS * DK / 4 / 256, 256, 0, stream>>>(num_part, den_part, out);
}

// Round 5
// 135.754 us; speedup vs baseline: 1.5471x; 1.1322x over previous
//
#include <hip/hip_runtime.h>

// B=4, S=4096, d_model=256, d_k=d_v=64
#define B_    4
#define S_    4096
#define DM    256
#define DK    64
#define NROWS (B_ * S_)        // 16384
#define LOG2E 1.4426950408889634f
// log2(1 + 2^-9): folded into the QK MFMA C-operand so that v_perm truncation
// of P becomes round-half-up; scale alpha cancels in num/den.
#define PACK_BIAS 0.0028151295f

typedef __attribute__((ext_vector_type(8))) short bfrag;   // 8 bf16 (4 VGPRs)
typedef __attribute__((ext_vector_type(4))) float ffrag;   // 4 f32 acc

// f32 -> bf16 round-to-nearest-even (prep-path only, not hot)
__device__ __forceinline__ unsigned bf16_rne_hi(float x) {
    unsigned u = __float_as_uint(x);
    return u + 0x7fffu + ((u >> 16) & 1u);
}
__device__ __forceinline__ unsigned short f2bf(float x) {
    return (unsigned short)(bf16_rne_hi(x) >> 16);
}
__device__ __forceinline__ unsigned pack_bf16x2(float lo, float hi) {
    return (bf16_rne_hi(hi) & 0xffff0000u) | (bf16_rne_hi(lo) >> 16);
}

// raw v_exp_f32 (scores bounded: no overflow guards needed)
__device__ __forceinline__ float fast_exp2(float x) {
#if __has_builtin(__builtin_amdgcn_exp2f)
    return __builtin_amdgcn_exp2f(x);
#else
    float r;
    asm("v_exp_f32 %0, %1\n\ts_nop 1" : "=v"(r) : "v"(x));
    return r;
#endif
}

// truncation-pack of two f32 into bf16x2 (1 VALU); inputs pre-scaled by
// (1+2^-9) via the MFMA C bias -> effective round-half-up.
__device__ __forceinline__ unsigned trunc_pack_bf16x2(float lo, float hi) {
    return __builtin_amdgcn_perm(__float_as_uint(hi), __float_as_uint(lo),
                                 0x07060302u);
}

// ---------------------------------------------------------------------------
// Fused prep + projection, one launch (768 blocks):
//   blocks 0..255  : vT2[b][t][d][pw] = bf16(v[b][key][d]) with per-32-tile
//                    pair permutation (pw=2c -> key c, pw=2c+1 -> key c+16),
//                    t = key/32. Tile-major layout gives attn imm-offset loads.
//   blocks 256..767: qp/kp = bf16(relu(x . w^T) * scale) via MFMA, 64 rows
//                    per block; w staged f32->bf16 in LDS (stride 264 ush ->
//                    2-way banks = free). q-scale folds (1/8)*log2(e).
// ---------------------------------------------------------------------------
__global__ __launch_bounds__(256) void fused_prep(
    const float* __restrict__ q, const float* __restrict__ k,
    const float* __restrict__ v, const float* __restrict__ wq,
    const float* __restrict__ wk, unsigned short* __restrict__ vT,
    unsigned short* __restrict__ qpb, unsigned short* __restrict__ kpb)
{
    __shared__ __align__(16) char smem[64 * 264 * 2];   // 33792 B (union)
    const int blk  = blockIdx.x;
    const int lane = threadIdx.x & 63, w = threadIdx.x >> 6;

    if (blk < 256) {
        // ---- vT2 transpose + permute ----
        float (*tile)[65] = (float(*)[65])smem;
        const int b = blk >> 6, s0 = (blk & 63) * 64;
#pragma unroll
        for (int i = 0; i < 16; ++i) {
            const int sl = i * 4 + w;
            tile[sl][lane] = v[(b * S_ + s0 + sl) * DK + lane];
        }
        __syncthreads();
        const int t32 = lane >> 5, pos = lane & 31;
        const int keyl = t32 * 32 + ((pos & 1) ? (pos >> 1) + 16 : (pos >> 1));
#pragma unroll
        for (int i = 0; i < 16; ++i) {
            const int d = i * 4 + w;
            vT[((size_t)(b * 128 + (s0 >> 5) + t32) * 64 + d) * 32 + pos] =
                f2bf(tile[keyl][d]);
        }
    } else {
        // ---- projection: 64 rows/block, wave = 16 rows ----
        unsigned short* wlds = (unsigned short*)smem;   // [64][264] bf16
        const int pb = blk - 256;                       // 0..511
        const int half = pb >> 8, rblk = pb & 255;
        const float* x;
        const float* wsrc;
        unsigned short* o;
        float scale;
        if (half == 0) { x = q; wsrc = wq; o = qpb; scale = 0.125f * LOG2E; }
        else           { x = k; wsrc = wk; o = kpb; scale = 1.0f; }

        // stage w (64x256 f32 -> bf16 LDS, stride 264)
#pragma unroll
        for (int i = 0; i < 16; ++i) {
            const int idx4 = i * 256 + threadIdx.x;     // float4 index, < 4096
            const int r = idx4 >> 6, c4 = idx4 & 63;
            const float4 wv = ((const float4*)wsrc)[idx4];
            uint2 pk;
            pk.x = pack_bf16x2(wv.x, wv.y);
            pk.y = pack_bf16x2(wv.z, wv.w);
            *(uint2*)&wlds[r * 264 + c4 * 4] = pk;
        }
        __syncthreads();

        const int m = lane & 15, quad = lane >> 4;
        const int rows0 = rblk * 64 + w * 16;
        const float* xrow = x + (size_t)(rows0 + m) * DM + quad * 8;

        ffrag acc[4];
#pragma unroll
        for (int dt = 0; dt < 4; ++dt) acc[dt] = (ffrag)(0.0f);

        float4 xb[2][2];
        xb[0][0] = ((const float4*)xrow)[0];
        xb[0][1] = ((const float4*)xrow)[1];

#pragma unroll 2
        for (int kf = 0; kf < 8; ++kf) {
            const int p = kf & 1;
            if (kf < 7) {
                const float4* xn = (const float4*)(xrow + (kf + 1) * 32);
                xb[p ^ 1][0] = xn[0];
                xb[p ^ 1][1] = xn[1];
            }
            union { bfrag v; unsigned u[4]; } pk;
            pk.u[0] = pack_bf16x2(xb[p][0].x, xb[p][0].y);
            pk.u[1] = pack_bf16x2(xb[p][0].z, xb[p][0].w);
            pk.u[2] = pack_bf16x2(xb[p][1].x, xb[p][1].y);
            pk.u[3] = pack_bf16x2(xb[p][1].z, xb[p][1].w);
#pragma unroll
            for (int dt = 0; dt < 4; ++dt) {
                const bfrag Bf = *(const bfrag*)&wlds[(dt * 16 + m) * 264 + kf * 32 + quad * 8];
                acc[dt] = __builtin_amdgcn_mfma_f32_16x16x32_bf16(pk.v, Bf, acc[dt], 0, 0, 0);
            }
        }
#pragma unroll
        for (int dt = 0; dt < 4; ++dt)
#pragma unroll
            for (int r = 0; r < 4; ++r)
                o[(rows0 + quad * 4 + r) * DK + dt * 16 + m] =
                    f2bf(fmaxf(acc[dt][r], 0.0f) * scale);
    }
}

// ---------------------------------------------------------------------------
// Attention, software-pipelined, VALU-lean:
//  - ping-pong kbuf/vbuf, unroll 2 (static indices, no spills)
//  - QK C-operand seeded with PACK_BIAS -> v_perm trunc-pack == round-half-up
//  - raw v_exp_f32; one stepped base pointer each for K and V (imm offsets)
//  - single P LDS buffer per wave (per-wave DS ops are in-order)
//  One-pass num/den (scores bounded); col-0 mask -> e = 0.
// ---------------------------------------------------------------------------
__global__ __launch_bounds__(256) void attn_mfma(
    const unsigned short* __restrict__ qp, const unsigned short* __restrict__ kp,
    const unsigned short* __restrict__ vT, float* __restrict__ num_part,
    float* __restrict__ den_part)
{
    __shared__ __align__(16) char smem[20480];   // P buffers (10240) U epilogue red
    unsigned short* Plds = (unsigned short*)smem;   // [4][32*40]
    float* red0 = (float*)smem;                      // epilogue: [2][2560]
    float* red1 = (float*)smem + 2560;

    const int lane = threadIdx.x & 63, w = threadIdx.x >> 6;
    const int m = lane & 15, quad = lane >> 4;
    const int qg = blockIdx.x;            // 0..511
    const int qbase = qg * 32;
    const int b = qg >> 7;
    const int kstart = (blockIdx.y * 4 + w) * 512;

    bfrag qa[2][2];
#pragma unroll
    for (int mt = 0; mt < 2; ++mt)
#pragma unroll
        for (int kf = 0; kf < 2; ++kf)
            qa[mt][kf] = *(const bfrag*)&qp[(qbase + mt * 16 + m) * DK + kf * 32 + quad * 8];

    ffrag oacc[2][4];
    float dacc[2][4];
#pragma unroll
    for (int mt = 0; mt < 2; ++mt) {
#pragma unroll
        for (int dt = 0; dt < 4; ++dt) oacc[mt][dt] = (ffrag)(0.0f);
#pragma unroll
        for (int r = 0; r < 4; ++r) dacc[mt][r] = 0.0f;
    }

    // stepped base pointers; all per-tile offsets are 13-bit imm-able
    const unsigned short* kptr = kp + ((size_t)b * S_ + kstart + m) * DK + quad * 8;
    const unsigned short* vptr = vT + ((size_t)(b * 128 + (kstart >> 5)) * 64 + m) * 32 + quad * 8;
    unsigned short* Pw = Plds + w * 1280;

    const ffrag cbias = (ffrag)(PACK_BIAS);

    // preload tile 0 into slot 0
    bfrag kbuf[2][2][2], vbuf[2][4];
#pragma unroll
    for (int kt = 0; kt < 2; ++kt)
#pragma unroll
        for (int kf = 0; kf < 2; ++kf)
            kbuf[0][kt][kf] = *(const bfrag*)(kptr + kt * 1024 + kf * 32);
#pragma unroll
    for (int dt = 0; dt < 4; ++dt)
        vbuf[0][dt] = *(const bfrag*)(vptr + dt * 512);

    bfrag pa0, pa1;

#pragma unroll 2
    for (int jj = 0; jj < 16; ++jj) {
        const int p = jj & 1;

        // 1) prefetch K(jj+1) -> kbuf[p^1]
        if (jj < 15) {
            const unsigned short* kn = kptr + (jj + 1) * 2048;
#pragma unroll
            for (int kt = 0; kt < 2; ++kt)
#pragma unroll
                for (int kf = 0; kf < 2; ++kf)
                    kbuf[p ^ 1][kt][kf] = *(const bfrag*)(kn + kt * 1024 + kf * 32);
        }

        // 2) PV(jj-1): pa + vbuf[p^1] (V(jj-1) dies here)
        if (jj > 0) {
#pragma unroll
            for (int dt = 0; dt < 4; ++dt) {
                oacc[0][dt] = __builtin_amdgcn_mfma_f32_16x16x32_bf16(pa0, vbuf[p ^ 1][dt], oacc[0][dt], 0, 0, 0);
                oacc[1][dt] = __builtin_amdgcn_mfma_f32_16x16x32_bf16(pa1, vbuf[p ^ 1][dt], oacc[1][dt], 0, 0, 0);
            }
        }

        // 3) prefetch V(jj+1) -> vbuf[p^1] (freed slot)
        if (jj < 15) {
            const unsigned short* vn = vptr + (jj + 1) * 2048;
#pragma unroll
            for (int dt = 0; dt < 4; ++dt)
                vbuf[p ^ 1][dt] = *(const bfrag*)(vn + dt * 512);
        }

        // 4) QK(jj) on kbuf[p]; C seeded with pack bias
        ffrag s[2][2];
#pragma unroll
        for (int mt = 0; mt < 2; ++mt)
#pragma unroll
            for (int kt = 0; kt < 2; ++kt) {
                ffrag t = __builtin_amdgcn_mfma_f32_16x16x32_bf16(qa[mt][0], kbuf[p][kt][0], cbias, 0, 0, 0);
                s[mt][kt] = __builtin_amdgcn_mfma_f32_16x16x32_bf16(qa[mt][1], kbuf[p][kt][1], t, 0, 0, 0);
            }

        // 5) exp (v_exp_f32), mask col 0, den, trunc-pack pairs -> LDS
        const bool mask0 = (jj == 0) && (kstart == 0) && (m == 0);
#pragma unroll
        for (int mt = 0; mt < 2; ++mt)
#pragma unroll
            for (int r = 0; r < 4; ++r) {
                float e0 = fast_exp2(s[mt][0][r]);
                float e1 = fast_exp2(s[mt][1][r]);
                if (mask0) e0 = 0.0f;
                dacc[mt][r] += e0 + e1;
                *(unsigned*)&Pw[(mt * 16 + quad * 4 + r) * 40 + m * 2] =
                    trunc_pack_bf16x2(e0, e1);
            }

        // 6) read P(jj) as A-frags (per-wave DS in-order)
        pa0 = *(const bfrag*)&Pw[(m) * 40 + quad * 8];
        pa1 = *(const bfrag*)&Pw[(16 + m) * 40 + quad * 8];
    }
    // final PV (tile 15): V(15) is in vbuf[1]
#pragma unroll
    for (int dt = 0; dt < 4; ++dt) {
        oacc[0][dt] = __builtin_amdgcn_mfma_f32_16x16x32_bf16(pa0, vbuf[1][dt], oacc[0][dt], 0, 0, 0);
        oacc[1][dt] = __builtin_amdgcn_mfma_f32_16x16x32_bf16(pa1, vbuf[1][dt], oacc[1][dt], 0, 0, 0);
    }

    // den: reduce over the 16 key-lanes within each quad group
#pragma unroll
    for (int mt = 0; mt < 2; ++mt)
#pragma unroll
        for (int r = 0; r < 4; ++r) {
            float d = dacc[mt][r];
            d += __shfl_xor(d, 1, 64);
            d += __shfl_xor(d, 2, 64);
            d += __shfl_xor(d, 4, 64);
            d += __shfl_xor(d, 8, 64);
            dacc[mt][r] = d;
        }

    // cross-wave tree reduce (reuses P LDS; P is dead)
    __syncthreads();
    float* red[2] = { red0, red1 };
    if (w >= 2) {
#pragma unroll
        for (int mt = 0; mt < 2; ++mt) {
#pragma unroll
            for (int dt = 0; dt < 4; ++dt)
#pragma unroll
                for (int r = 0; r < 4; ++r)
                    red[w - 2][((mt * 4 + dt) * 4 + r) * 64 + lane] = oacc[mt][dt][r];
#pragma unroll
            for (int r = 0; r < 4; ++r)
                red[w - 2][2048 + (mt * 4 + r) * 64 + lane] = dacc[mt][r];
        }
    }
    __syncthreads();
    if (w < 2) {
#pragma unroll
        for (int mt = 0; mt < 2; ++mt) {
#pragma unroll
            for (int dt = 0; dt < 4; ++dt)
#pragma unroll
                for (int r = 0; r < 4; ++r)
                    oacc[mt][dt][r] += red[w][((mt * 4 + dt) * 4 + r) * 64 + lane];
#pragma unroll
            for (int r = 0; r < 4; ++r)
                dacc[mt][r] += red[w][2048 + (mt * 4 + r) * 64 + lane];
        }
    }
    __syncthreads();
    if (w == 1) {
#pragma unroll
        for (int mt = 0; mt < 2; ++mt) {
#pragma unroll
            for (int dt = 0; dt < 4; ++dt)
#pragma unroll
                for (int r = 0; r < 4; ++r)
                    red0[((mt * 4 + dt) * 4 + r) * 64 + lane] = oacc[mt][dt][r];
#pragma unroll
            for (int r = 0; r < 4; ++r)
                red0[2048 + (mt * 4 + r) * 64 + lane] = dacc[mt][r];
        }
    }
    __syncthreads();
    if (w == 0) {
        const int gy = blockIdx.y;
#pragma unroll
        for (int mt = 0; mt < 2; ++mt) {
#pragma unroll
            for (int dt = 0; dt < 4; ++dt)
#pragma unroll
                for (int r = 0; r < 4; ++r) {
                    const float nv = oacc[mt][dt][r] + red0[((mt * 4 + dt) * 4 + r) * 64 + lane];
                    num_part[(size_t)gy * NROWS * DK +
                             (qbase + mt * 16 + quad * 4 + r) * DK + dt * 16 + m] = nv;
                }
#pragma unroll
            for (int r = 0; r < 4; ++r) {
                const float dv = dacc[mt][r] + red0[2048 + (mt * 4 + r) * 64 + lane];
                if (m == 0)
                    den_part[gy * NROWS + qbase + mt * 16 + quad * 4 + r] = dv;
            }
        }
    }
}

// ---------------------------------------------------------------------------
__global__ __launch_bounds__(256) void finalize_kernel(
    const float* __restrict__ num_part, const float* __restrict__ den_part,
    float* __restrict__ out)
{
    const int i4 = blockIdx.x * 256 + threadIdx.x;   // float4 index, < 262144
    const int row = i4 >> 4;
    const float4 a = ((const float4*)num_part)[i4];
    const float4 c = ((const float4*)(num_part + (size_t)NROWS * DK))[i4];
    const float inv = 1.0f / (den_part[row] + den_part[NROWS + row]);
    float4 o;
    o.x = (a.x + c.x) * inv;
    o.y = (a.y + c.y) * inv;
    o.z = (a.z + c.z) * inv;
    o.w = (a.w + c.w) * inv;
    ((float4*)out)[i4] = o;
}

// ---------------------------------------------------------------------------
extern "C" void kernel_launch(void* const* d_in, const int* in_sizes, int n_in,
                              void* d_out, int out_size, void* d_ws, size_t ws_size,
                              hipStream_t stream)
{
    const float* q  = (const float*)d_in[0];
    const float* k  = (const float*)d_in[1];
    const float* v  = (const float*)d_in[2];
    const float* wq = (const float*)d_in[3];
    const float* wk = (const float*)d_in[4];
    float* out = (float*)d_out;

    // ws: qpb 2M | kpb 2M | vT 2M | num_part 8M | den_part 128K
    char* p = (char*)d_ws;
    unsigned short* qpb = (unsigned short*)p;   p += (size_t)NROWS * DK * 2;
    unsigned short* kpb = (unsigned short*)p;   p += (size_t)NROWS * DK * 2;
    unsigned short* vT  = (unsigned short*)p;   p += (size_t)B_ * DK * S_ * 2;
    float* num_part     = (float*)p;            p += (size_t)2 * NROWS * DK * 4;
    float* den_part     = (float*)p;

    fused_prep<<<768, 256, 0, stream>>>(q, k, v, wq, wk, vT, qpb, kpb);
    attn_mfma<<<dim3(512, 2), 256, 0, stream>>>(qpb, kpb, vT, num_part, den_part);
    finalize_kernel<<<NROWS * DK / 4 / 256, 256, 0, stream>>>(num_part, den_part, out);
}